// Round 6
// baseline (2446.686 us; speedup 1.0000x reference)
//
#include <hip/hip_runtime.h>
#include <math.h>

#define B_ 4
#define L_ 1024
#define D_ 1024
#define H_ 16
#define DH_ 64
#define M_ (B_*L_)   // 4096 rows

// ---------------- fp32 128x128-tile GEMM, BK=16, reg-prefetch ----------------
__device__ __forceinline__ void gemm128_body(const float* __restrict__ A,
                                             const float* __restrict__ W,
                                             const float* __restrict__ bias,
                                             float* __restrict__ C) {
  __shared__ float As[16][128];
  __shared__ float Bs[16][128];
  const int t = threadIdx.x;
  const int bm = blockIdx.y * 128, bn = blockIdx.x * 128;
  const int tx = t & 15, ty = t >> 4;
  float acc[8][8];
#pragma unroll
  for (int i = 0; i < 8; i++)
#pragma unroll
    for (int j = 0; j < 8; j++) acc[i][j] = 0.f;
  const int ar = t >> 1, ac = (t & 1) * 8;
  const int wr = t >> 4, wc = (t & 15) * 8;
  const float* Ap = A + (size_t)(bm + ar) * 1024 + ac;
  const float* Wp = W + (size_t)wr * 1024 + bn + wc;
  float4 a0 = *(const float4*)(Ap);
  float4 a1 = *(const float4*)(Ap + 4);
  float4 w0 = *(const float4*)(Wp);
  float4 w1 = *(const float4*)(Wp + 4);
  for (int k0 = 0; k0 < 1024; k0 += 16) {
    __syncthreads();
    As[ac + 0][ar] = a0.x; As[ac + 1][ar] = a0.y;
    As[ac + 2][ar] = a0.z; As[ac + 3][ar] = a0.w;
    As[ac + 4][ar] = a1.x; As[ac + 5][ar] = a1.y;
    As[ac + 6][ar] = a1.z; As[ac + 7][ar] = a1.w;
    *(float4*)&Bs[wr][wc] = w0;
    *(float4*)&Bs[wr][wc + 4] = w1;
    __syncthreads();
    if (k0 + 16 < 1024) {
      a0 = *(const float4*)(Ap + k0 + 16);
      a1 = *(const float4*)(Ap + k0 + 20);
      w0 = *(const float4*)(Wp + (size_t)(k0 + 16) * 1024);
      w1 = *(const float4*)(Wp + (size_t)(k0 + 16) * 1024 + 4);
    }
#pragma unroll
    for (int k = 0; k < 16; k++) {
      float4 x0 = *(const float4*)&As[k][ty * 8];
      float4 x1 = *(const float4*)&As[k][ty * 8 + 4];
      float4 y0 = *(const float4*)&Bs[k][tx * 8];
      float4 y1 = *(const float4*)&Bs[k][tx * 8 + 4];
      float a_[8] = {x0.x, x0.y, x0.z, x0.w, x1.x, x1.y, x1.z, x1.w};
      float b_[8] = {y0.x, y0.y, y0.z, y0.w, y1.x, y1.y, y1.z, y1.w};
#pragma unroll
      for (int i = 0; i < 8; i++)
#pragma unroll
        for (int j = 0; j < 8; j++)
          acc[i][j] = fmaf(a_[i], b_[j], acc[i][j]);
    }
  }
#pragma unroll
  for (int i = 0; i < 8; i++) {
    int m = bm + ty * 8 + i;
    float* Cp = C + (size_t)m * 1024 + bn + tx * 8;
    const float* bp = bias + bn + tx * 8;
#pragma unroll
    for (int j = 0; j < 8; j++) Cp[j] = acc[i][j] + bp[j];
  }
}

__global__ __launch_bounds__(256) void gemm_qkv(const float* __restrict__ x,
                                                const float* __restrict__ Wq, const float* __restrict__ bq, float* __restrict__ qf,
                                                const float* __restrict__ Wk, const float* __restrict__ bk, float* __restrict__ kf,
                                                const float* __restrict__ Wv, const float* __restrict__ bv, float* __restrict__ vf) {
  const int z = blockIdx.z;
  const float* W = (z == 0) ? Wq : (z == 1) ? Wk : Wv;
  const float* bb = (z == 0) ? bq : (z == 1) ? bk : bv;
  float* C = (z == 0) ? qf : (z == 1) ? kf : vf;
  gemm128_body(x, W, bb, C);
}

__global__ __launch_bounds__(256) void gemm_out(const float* __restrict__ A,
                                                const float* __restrict__ W,
                                                const float* __restrict__ bias,
                                                float* __restrict__ C) {
  gemm128_body(A, W, bias, C);
}

// ---------------- attention: q in SGPRs, row-major K tile, b128 LDS reads ----------------
// grid: 16384 = 256 i-chunks x 16 h x 4 b; block 256 = 4 waves, wave = one q-row.
// VGPR target <= 64 -> 8 waves/SIMD (occupancy cap 100%).
__global__ __launch_bounds__(256) void attn_topk_f32(const float* __restrict__ qf,
                                                     const float* __restrict__ kf,
                                                     const float* __restrict__ vf,
                                                     float* __restrict__ aw) {
  __shared__ float ks[64][66];   // row-major K chunk: [j][d], pad 66 (2-way alias = free)
  const int t = threadIdx.x;
  const int lane = t & 63;
  const int w = t >> 6;
  const int blk = blockIdx.x;
  const int ib = (blk & 255) * 4;
  const int h = (blk >> 8) & 15;
  const int b = blk >> 12;
  const int i = ib + w;
  const size_t rowbase = (size_t)b * L_;

  // q row -> 64 SGPRs (wave-uniform row; v_readlane with imm lane)
  int qi[64];
  {
    union { float f; int i; } uu;
    uu.f = qf[(rowbase + i) * D_ + h * DH_ + lane];
#pragma unroll
    for (int p = 0; p < 64; p++) qi[p] = __builtin_amdgcn_readlane(uu.i, p);
  }

  const int jj = t >> 2;                 // 0..63: j within chunk this thread stages
  const int dseg = (t & 3) * 16;         // 16-float segment
  const float* kb = kf + rowbase * D_ + h * DH_;

  float4 ld[4];
  {
    const float* p = kb + (size_t)jj * D_ + dseg;
#pragma unroll
    for (int r = 0; r < 4; r++) ld[r] = ((const float4*)p)[r];
  }

  float sc[16];
  for (int c = 0; c < 16; ++c) {
    __syncthreads();   // prev dot reads done
    *(float4*)&ks[jj][dseg]      = ld[0];
    *(float4*)&ks[jj][dseg + 4]  = ld[1];
    *(float4*)&ks[jj][dseg + 8]  = ld[2];
    *(float4*)&ks[jj][dseg + 12] = ld[3];
    __syncthreads();
    if (c < 15) {
      const float* p = kb + (size_t)((c + 1) * 64 + jj) * D_ + dseg;
#pragma unroll
      for (int r = 0; r < 4; r++) ld[r] = ((const float4*)p)[r];
    }
    // dot: lane computes score for j = c*64 + lane; b128 row reads, q from SGPRs.
    // Term order identical to R4/R5: a0..a3 hold d%4 classes, ascending p.
    const float* krow = &ks[lane][0];
    float a0 = 0.f, a1 = 0.f, a2 = 0.f, a3 = 0.f;
#pragma unroll
    for (int p = 0; p < 16; p++) {
      float4 kv = *(const float4*)(krow + 4 * p);
      a0 = fmaf(kv.x, __int_as_float(qi[4 * p + 0]), a0);
      a1 = fmaf(kv.y, __int_as_float(qi[4 * p + 1]), a1);
      a2 = fmaf(kv.z, __int_as_float(qi[4 * p + 2]), a2);
      a3 = fmaf(kv.w, __int_as_float(qi[4 * p + 3]), a3);
    }
    sc[c] = ((a0 + a1) + (a2 + a3)) * 0.125f;   // 1/sqrt(64), exact
  }

  // ---- max
  float mx = sc[0];
#pragma unroll
  for (int u = 1; u < 16; u++) mx = fmaxf(mx, sc[u]);
#pragma unroll
  for (int off = 32; off >= 1; off >>= 1) mx = fmaxf(mx, __shfl_xor(mx, off, 64));

  // ---- bisection: invariant cnt(>=lo) >= 32 > cnt(>=hi)
  float lo = mx - 64.f, hi = mx;
  for (int it = 0; it < 16; ++it) {
    float mid = 0.5f * (lo + hi);
    int cnt = 0;
#pragma unroll
    for (int u = 0; u < 16; u++) cnt += __popcll(__ballot(sc[u] >= mid));
    if (cnt >= 32) lo = mid; else hi = mid;
  }
  // ---- descend to exact rank-31 value (0-indexed), duplicate-aware
  int cabove = 0;
#pragma unroll
  for (int u = 0; u < 16; u++) cabove += __popcll(__ballot(sc[u] >= hi));
  float v31 = hi;
  while (cabove < 32) {
    float nx = -INFINITY;
#pragma unroll
    for (int u = 0; u < 16; u++) nx = fmaxf(nx, (sc[u] < v31) ? sc[u] : -INFINITY);
#pragma unroll
    for (int off = 32; off >= 1; off >>= 1) nx = fmaxf(nx, __shfl_xor(nx, off, 64));
    int ceq = 0;
#pragma unroll
    for (int u = 0; u < 16; u++) ceq += __popcll(__ballot(sc[u] == nx));
    cabove += ceq;
    v31 = nx;
  }
  int c_eq = 0;
#pragma unroll
  for (int u = 0; u < 16; u++) c_eq += __popcll(__ballot(sc[u] == v31));
  const int c_gt = cabove - c_eq;
  const bool span = (cabove > 32);
  const int keep_eq = 32 - c_gt;
  float v32;
  if (span) {
    v32 = v31;
  } else {
    float nx = -INFINITY;
#pragma unroll
    for (int u = 0; u < 16; u++) nx = fmaxf(nx, (sc[u] < v31) ? sc[u] : -INFINITY);
#pragma unroll
    for (int off = 32; off >= 1; off >>= 1) nx = fmaxf(nx, __shfl_xor(nx, off, 64));
    v32 = nx;
  }
  const float tau = 0.5f * (v31 + v32);
  const float invbeta = 166666.67f;   // 1 / 6e-6

  // ---- Z
  float z = 0.f;
#pragma unroll
  for (int u = 0; u < 16; u++) z += __expf(sc[u] - mx);
#pragma unroll
  for (int off = 32; off >= 1; off >>= 1) z += __shfl_xor(z, off, 64);

  // ---- enumerate candidates, weight, accumulate V
  const float cutoff = fminf(tau - 1.8e-4f, v31);
  const float* vcol = vf + rowbase * D_ + h * DH_ + lane;
  float S = 0.f, acc = 0.f;
  int eq_seen = 0;
  for (int u = 0; u < 16; ++u) {
    unsigned long long mask = __ballot(sc[u] >= cutoff);
    while (mask) {
      int l2 = (int)__builtin_ctzll(mask);
      mask &= mask - 1;
      float s = __shfl(sc[u], l2, 64);
      float e = __expf(s - mx);
      float f;
      if (span) {
        if (s > v31) f = 1.f;
        else if (s == v31) { f = (eq_seen < keep_eq) ? 1.f : 0.f; ++eq_seen; }
        else f = 0.f;
      } else {
        float arg = (s - tau) * invbeta;
        f = (arg > 30.f) ? 1.f : ((arg < -30.f) ? 0.f : 1.f / (1.f + __expf(-arg)));
      }
      float fe = f * e;
      S += fe;
      acc = fmaf(fe, vcol[(size_t)(u * 64 + l2) * D_], acc);
    }
  }
  aw[(rowbase + i) * D_ + h * DH_ + lane] = acc / (S + 1e-8f * z);
}

extern "C" void kernel_launch(void* const* d_in, const int* in_sizes, int n_in,
                              void* d_out, int out_size, void* d_ws, size_t ws_size,
                              hipStream_t stream) {
  const float* x  = (const float*)d_in[0];
  const float* Wq = (const float*)d_in[1];
  const float* bq = (const float*)d_in[2];
  const float* Wk = (const float*)d_in[3];
  const float* bk = (const float*)d_in[4];
  const float* Wv = (const float*)d_in[5];
  const float* bv = (const float*)d_in[6];
  const float* Wo = (const float*)d_in[7];
  const float* bo = (const float*)d_in[8];
  float* out = (float*)d_out;

  const size_t MD = (size_t)M_ * D_;
  float* qf = (float*)d_ws;            // ws >= 96 MiB established (R1/R2 fp64 path ran)
  float* kf = qf + MD;
  float* vf = kf + MD;
  float* aw = vf + MD;

  dim3 b256(256);
  dim3 gqkv(8, 32, 3);
  dim3 g128(8, 32);
  dim3 gattn(16384);

  hipLaunchKernelGGL(gemm_qkv, gqkv, b256, 0, stream,
                     x, Wq, bq, qf, Wk, bk, kf, Wv, bv, vf);
  hipLaunchKernelGGL(attn_topk_f32, gattn, b256, 0, stream, qf, kf, vf, aw);
  hipLaunchKernelGGL(gemm_out, g128, b256, 0, stream, aw, Wo, bo, out);
}

// Round 7
// 1071.352 us; speedup vs baseline: 2.2837x; 2.2837x over previous
//
#include <hip/hip_runtime.h>
#include <math.h>

#define B_ 4
#define L_ 1024
#define D_ 1024
#define H_ 16
#define DH_ 64
#define M_ (B_*L_)   // 4096 rows

// ---------------- fp32 128x128-tile GEMM, BK=16, reg-prefetch ----------------
__device__ __forceinline__ void gemm128_body(const float* __restrict__ A,
                                             const float* __restrict__ W,
                                             const float* __restrict__ bias,
                                             float* __restrict__ C) {
  __shared__ float As[16][128];
  __shared__ float Bs[16][128];
  const int t = threadIdx.x;
  const int bm = blockIdx.y * 128, bn = blockIdx.x * 128;
  const int tx = t & 15, ty = t >> 4;
  float acc[8][8];
#pragma unroll
  for (int i = 0; i < 8; i++)
#pragma unroll
    for (int j = 0; j < 8; j++) acc[i][j] = 0.f;
  const int ar = t >> 1, ac = (t & 1) * 8;
  const int wr = t >> 4, wc = (t & 15) * 8;
  const float* Ap = A + (size_t)(bm + ar) * 1024 + ac;
  const float* Wp = W + (size_t)wr * 1024 + bn + wc;
  float4 a0 = *(const float4*)(Ap);
  float4 a1 = *(const float4*)(Ap + 4);
  float4 w0 = *(const float4*)(Wp);
  float4 w1 = *(const float4*)(Wp + 4);
  for (int k0 = 0; k0 < 1024; k0 += 16) {
    __syncthreads();
    As[ac + 0][ar] = a0.x; As[ac + 1][ar] = a0.y;
    As[ac + 2][ar] = a0.z; As[ac + 3][ar] = a0.w;
    As[ac + 4][ar] = a1.x; As[ac + 5][ar] = a1.y;
    As[ac + 6][ar] = a1.z; As[ac + 7][ar] = a1.w;
    *(float4*)&Bs[wr][wc] = w0;
    *(float4*)&Bs[wr][wc + 4] = w1;
    __syncthreads();
    if (k0 + 16 < 1024) {
      a0 = *(const float4*)(Ap + k0 + 16);
      a1 = *(const float4*)(Ap + k0 + 20);
      w0 = *(const float4*)(Wp + (size_t)(k0 + 16) * 1024);
      w1 = *(const float4*)(Wp + (size_t)(k0 + 16) * 1024 + 4);
    }
#pragma unroll
    for (int k = 0; k < 16; k++) {
      float4 x0 = *(const float4*)&As[k][ty * 8];
      float4 x1 = *(const float4*)&As[k][ty * 8 + 4];
      float4 y0 = *(const float4*)&Bs[k][tx * 8];
      float4 y1 = *(const float4*)&Bs[k][tx * 8 + 4];
      float a_[8] = {x0.x, x0.y, x0.z, x0.w, x1.x, x1.y, x1.z, x1.w};
      float b_[8] = {y0.x, y0.y, y0.z, y0.w, y1.x, y1.y, y1.z, y1.w};
#pragma unroll
      for (int i = 0; i < 8; i++)
#pragma unroll
        for (int j = 0; j < 8; j++)
          acc[i][j] = fmaf(a_[i], b_[j], acc[i][j]);
    }
  }
#pragma unroll
  for (int i = 0; i < 8; i++) {
    int m = bm + ty * 8 + i;
    float* Cp = C + (size_t)m * 1024 + bn + tx * 8;
    const float* bp = bias + bn + tx * 8;
#pragma unroll
    for (int j = 0; j < 8; j++) Cp[j] = acc[i][j] + bp[j];
  }
}

__global__ __launch_bounds__(256) void gemm_qkv(const float* __restrict__ x,
                                                const float* __restrict__ Wq, const float* __restrict__ bq, float* __restrict__ qf,
                                                const float* __restrict__ Wk, const float* __restrict__ bk, float* __restrict__ kf,
                                                const float* __restrict__ Wv, const float* __restrict__ bv, float* __restrict__ vf) {
  const int z = blockIdx.z;
  const float* W = (z == 0) ? Wq : (z == 1) ? Wk : Wv;
  const float* bb = (z == 0) ? bq : (z == 1) ? bk : bv;
  float* C = (z == 0) ? qf : (z == 1) ? kf : vf;
  gemm128_body(x, W, bb, C);
}

__global__ __launch_bounds__(256) void gemm_out(const float* __restrict__ A,
                                                const float* __restrict__ W,
                                                const float* __restrict__ bias,
                                                float* __restrict__ C) {
  gemm128_body(A, W, bias, C);
}

// ---------------- attention: d-split cooperative, K direct from L2 ----------------
// grid: 16384 = 256 i-chunks x 16 h x 4 b; block 256 = 4 waves.
// Block owns 4 q-rows. Wave w owns d-slice [16w,16w+16): reads K[j] slice from
// global (L2-resident head, 256 KB) and computes 16-d partial dots for all 4
// rows; partials summed across waves via small double-buffered LDS (1 barrier
// per 64-j chunk). Wave w then runs selection for row ib+w (scores sc[16]).
__global__ __launch_bounds__(256) void attn_topk_f32(const float* __restrict__ qf,
                                                     const float* __restrict__ kf,
                                                     const float* __restrict__ vf,
                                                     float* __restrict__ aw) {
  __shared__ float part[2][4][4][64];   // [buf][src wave u][row r][j]  (8 KB)
  __shared__ float qsh[4][64];
  const int t = threadIdx.x;
  const int lane = t & 63;
  const int w = t >> 6;
  const int blk = blockIdx.x;
  const int ib = (blk & 255) * 4;
  const int h = (blk >> 8) & 15;
  const int b = blk >> 12;
  const size_t rowbase = (size_t)b * L_;

  { int r = t >> 6, d = t & 63; qsh[r][d] = qf[(rowbase + ib + r) * D_ + h * DH_ + d]; }
  __syncthreads();

  // this wave's q fragments: 4 rows x 16 d (uniform b128 LDS reads, 64 VGPRs)
  float qr[4][16];
#pragma unroll
  for (int r = 0; r < 4; r++)
#pragma unroll
    for (int p = 0; p < 4; p++) {
      float4 v = *(const float4*)&qsh[r][16 * w + 4 * p];
      qr[r][4 * p + 0] = v.x; qr[r][4 * p + 1] = v.y;
      qr[r][4 * p + 2] = v.z; qr[r][4 * p + 3] = v.w;
    }

  // K base for this wave's d-slice; lane j reads row (c*64+j), 16 floats
  const float* kb = kf + rowbase * D_ + h * DH_ + 16 * w;

  float sc[16];
  for (int c = 0; c < 16; ++c) {
    const float* kp = kb + (size_t)(c * 64 + lane) * D_;
    float4 a0 = *(const float4*)(kp);
    float4 a1 = *(const float4*)(kp + 4);
    float4 a2 = *(const float4*)(kp + 8);
    float4 a3 = *(const float4*)(kp + 12);
    float ps[4];
#pragma unroll
    for (int r = 0; r < 4; r++) {
      float s = 0.f;
      s = fmaf(a0.x, qr[r][0],  s); s = fmaf(a0.y, qr[r][1],  s);
      s = fmaf(a0.z, qr[r][2],  s); s = fmaf(a0.w, qr[r][3],  s);
      s = fmaf(a1.x, qr[r][4],  s); s = fmaf(a1.y, qr[r][5],  s);
      s = fmaf(a1.z, qr[r][6],  s); s = fmaf(a1.w, qr[r][7],  s);
      s = fmaf(a2.x, qr[r][8],  s); s = fmaf(a2.y, qr[r][9],  s);
      s = fmaf(a2.z, qr[r][10], s); s = fmaf(a2.w, qr[r][11], s);
      s = fmaf(a3.x, qr[r][12], s); s = fmaf(a3.y, qr[r][13], s);
      s = fmaf(a3.z, qr[r][14], s); s = fmaf(a3.w, qr[r][15], s);
      ps[r] = s;
    }
    const int pb = c & 1;
    part[pb][w][0][lane] = ps[0];
    part[pb][w][1][lane] = ps[1];
    part[pb][w][2][lane] = ps[2];
    part[pb][w][3][lane] = ps[3];
    __syncthreads();
    // wave w assembles full scores for ITS row (ib+w), j = c*64+lane
    sc[c] = ((part[pb][0][w][lane] + part[pb][1][w][lane]) +
             (part[pb][2][w][lane] + part[pb][3][w][lane])) * 0.125f;
  }

  // ---- selection (identical to R5) ----
  float mx = sc[0];
#pragma unroll
  for (int u = 1; u < 16; u++) mx = fmaxf(mx, sc[u]);
#pragma unroll
  for (int off = 32; off >= 1; off >>= 1) mx = fmaxf(mx, __shfl_xor(mx, off, 64));

  float lo = mx - 64.f, hi = mx;
  for (int it = 0; it < 16; ++it) {
    float mid = 0.5f * (lo + hi);
    int cnt = 0;
#pragma unroll
    for (int u = 0; u < 16; u++) cnt += __popcll(__ballot(sc[u] >= mid));
    if (cnt >= 32) lo = mid; else hi = mid;
  }
  int cabove = 0;
#pragma unroll
  for (int u = 0; u < 16; u++) cabove += __popcll(__ballot(sc[u] >= hi));
  float v31 = hi;
  while (cabove < 32) {
    float nx = -INFINITY;
#pragma unroll
    for (int u = 0; u < 16; u++) nx = fmaxf(nx, (sc[u] < v31) ? sc[u] : -INFINITY);
#pragma unroll
    for (int off = 32; off >= 1; off >>= 1) nx = fmaxf(nx, __shfl_xor(nx, off, 64));
    int ceq = 0;
#pragma unroll
    for (int u = 0; u < 16; u++) ceq += __popcll(__ballot(sc[u] == nx));
    cabove += ceq;
    v31 = nx;
  }
  int c_eq = 0;
#pragma unroll
  for (int u = 0; u < 16; u++) c_eq += __popcll(__ballot(sc[u] == v31));
  const int c_gt = cabove - c_eq;
  const bool span = (cabove > 32);
  const int keep_eq = 32 - c_gt;
  float v32;
  if (span) {
    v32 = v31;
  } else {
    float nx = -INFINITY;
#pragma unroll
    for (int u = 0; u < 16; u++) nx = fmaxf(nx, (sc[u] < v31) ? sc[u] : -INFINITY);
#pragma unroll
    for (int off = 32; off >= 1; off >>= 1) nx = fmaxf(nx, __shfl_xor(nx, off, 64));
    v32 = nx;
  }
  const float tau = 0.5f * (v31 + v32);
  const float invbeta = 166666.67f;   // 1 / 6e-6

  float z = 0.f;
#pragma unroll
  for (int u = 0; u < 16; u++) z += __expf(sc[u] - mx);
#pragma unroll
  for (int off = 32; off >= 1; off >>= 1) z += __shfl_xor(z, off, 64);

  const float cutoff = fminf(tau - 1.8e-4f, v31);
  const float* vcol = vf + rowbase * D_ + h * DH_ + lane;
  float S = 0.f, acc = 0.f;
  int eq_seen = 0;
  for (int u = 0; u < 16; ++u) {
    unsigned long long mask = __ballot(sc[u] >= cutoff);
    while (mask) {
      int l2 = (int)__builtin_ctzll(mask);
      mask &= mask - 1;
      float s = __shfl(sc[u], l2, 64);
      float e = __expf(s - mx);
      float f;
      if (span) {
        if (s > v31) f = 1.f;
        else if (s == v31) { f = (eq_seen < keep_eq) ? 1.f : 0.f; ++eq_seen; }
        else f = 0.f;
      } else {
        float arg = (s - tau) * invbeta;
        f = (arg > 30.f) ? 1.f : ((arg < -30.f) ? 0.f : 1.f / (1.f + __expf(-arg)));
      }
      float fe = f * e;
      S += fe;
      acc = fmaf(fe, vcol[(size_t)(u * 64 + l2) * D_], acc);
    }
  }
  aw[(rowbase + ib + w) * D_ + h * DH_ + lane] = acc / (S + 1e-8f * z);
}

extern "C" void kernel_launch(void* const* d_in, const int* in_sizes, int n_in,
                              void* d_out, int out_size, void* d_ws, size_t ws_size,
                              hipStream_t stream) {
  const float* x  = (const float*)d_in[0];
  const float* Wq = (const float*)d_in[1];
  const float* bq = (const float*)d_in[2];
  const float* Wk = (const float*)d_in[3];
  const float* bk = (const float*)d_in[4];
  const float* Wv = (const float*)d_in[5];
  const float* bv = (const float*)d_in[6];
  const float* Wo = (const float*)d_in[7];
  const float* bo = (const float*)d_in[8];
  float* out = (float*)d_out;

  const size_t MD = (size_t)M_ * D_;
  float* qf = (float*)d_ws;            // ws >= 96 MiB established
  float* kf = qf + MD;
  float* vf = kf + MD;
  float* aw = vf + MD;

  dim3 b256(256);
  dim3 gqkv(8, 32, 3);
  dim3 g128(8, 32);
  dim3 gattn(16384);

  hipLaunchKernelGGL(gemm_qkv, gqkv, b256, 0, stream,
                     x, Wq, bq, qf, Wk, bk, kf, Wv, bv, vf);
  hipLaunchKernelGGL(attn_topk_f32, gattn, b256, 0, stream, qf, kf, vf, aw);
  hipLaunchKernelGGL(gemm_out, g128, b256, 0, stream, aw, Wo, bo, out);
}

// Round 8
// 951.584 us; speedup vs baseline: 2.5712x; 1.1259x over previous
//
#include <hip/hip_runtime.h>
#include <math.h>

#define B_ 4
#define L_ 1024
#define D_ 1024
#define H_ 16
#define DH_ 64
#define M_ (B_*L_)   // 4096 rows

// ---------------- fp32 128x128-tile GEMM, BK=16, reg-prefetch ----------------
__device__ __forceinline__ void gemm128_body(const float* __restrict__ A,
                                             const float* __restrict__ W,
                                             const float* __restrict__ bias,
                                             float* __restrict__ C) {
  __shared__ float As[16][128];
  __shared__ float Bs[16][128];
  const int t = threadIdx.x;
  const int bm = blockIdx.y * 128, bn = blockIdx.x * 128;
  const int tx = t & 15, ty = t >> 4;
  float acc[8][8];
#pragma unroll
  for (int i = 0; i < 8; i++)
#pragma unroll
    for (int j = 0; j < 8; j++) acc[i][j] = 0.f;
  const int ar = t >> 1, ac = (t & 1) * 8;
  const int wr = t >> 4, wc = (t & 15) * 8;
  const float* Ap = A + (size_t)(bm + ar) * 1024 + ac;
  const float* Wp = W + (size_t)wr * 1024 + bn + wc;
  float4 a0 = *(const float4*)(Ap);
  float4 a1 = *(const float4*)(Ap + 4);
  float4 w0 = *(const float4*)(Wp);
  float4 w1 = *(const float4*)(Wp + 4);
  for (int k0 = 0; k0 < 1024; k0 += 16) {
    __syncthreads();
    As[ac + 0][ar] = a0.x; As[ac + 1][ar] = a0.y;
    As[ac + 2][ar] = a0.z; As[ac + 3][ar] = a0.w;
    As[ac + 4][ar] = a1.x; As[ac + 5][ar] = a1.y;
    As[ac + 6][ar] = a1.z; As[ac + 7][ar] = a1.w;
    *(float4*)&Bs[wr][wc] = w0;
    *(float4*)&Bs[wr][wc + 4] = w1;
    __syncthreads();
    if (k0 + 16 < 1024) {
      a0 = *(const float4*)(Ap + k0 + 16);
      a1 = *(const float4*)(Ap + k0 + 20);
      w0 = *(const float4*)(Wp + (size_t)(k0 + 16) * 1024);
      w1 = *(const float4*)(Wp + (size_t)(k0 + 16) * 1024 + 4);
    }
#pragma unroll
    for (int k = 0; k < 16; k++) {
      float4 x0 = *(const float4*)&As[k][ty * 8];
      float4 x1 = *(const float4*)&As[k][ty * 8 + 4];
      float4 y0 = *(const float4*)&Bs[k][tx * 8];
      float4 y1 = *(const float4*)&Bs[k][tx * 8 + 4];
      float a_[8] = {x0.x, x0.y, x0.z, x0.w, x1.x, x1.y, x1.z, x1.w};
      float b_[8] = {y0.x, y0.y, y0.z, y0.w, y1.x, y1.y, y1.z, y1.w};
#pragma unroll
      for (int i = 0; i < 8; i++)
#pragma unroll
        for (int j = 0; j < 8; j++)
          acc[i][j] = fmaf(a_[i], b_[j], acc[i][j]);
    }
  }
#pragma unroll
  for (int i = 0; i < 8; i++) {
    int m = bm + ty * 8 + i;
    float* Cp = C + (size_t)m * 1024 + bn + tx * 8;
    const float* bp = bias + bn + tx * 8;
#pragma unroll
    for (int j = 0; j < 8; j++) Cp[j] = acc[i][j] + bp[j];
  }
}

__global__ __launch_bounds__(256) void gemm_qkv(const float* __restrict__ x,
                                                const float* __restrict__ Wq, const float* __restrict__ bq, float* __restrict__ qf,
                                                const float* __restrict__ Wk, const float* __restrict__ bk, float* __restrict__ kf,
                                                const float* __restrict__ Wv, const float* __restrict__ bv, float* __restrict__ vf) {
  const int z = blockIdx.z;
  const float* W = (z == 0) ? Wq : (z == 1) ? Wk : Wv;
  const float* bb = (z == 0) ? bq : (z == 1) ? bk : bv;
  float* C = (z == 0) ? qf : (z == 1) ? kf : vf;
  gemm128_body(x, W, bb, C);
}

__global__ __launch_bounds__(256) void gemm_out(const float* __restrict__ A,
                                                const float* __restrict__ W,
                                                const float* __restrict__ bias,
                                                float* __restrict__ C) {
  gemm128_body(A, W, bias, C);
}

// ---------------- K transpose per head: kf[b*L+j][h*64+d] -> kT[((b*16+h)*64+d)*1024+j] ----------------
__global__ __launch_bounds__(256) void transpose_k(const float* __restrict__ kf,
                                                   float* __restrict__ kT) {
  __shared__ float tile[64][65];
  const int t = threadIdx.x;
  const int j0 = (blockIdx.x & 15) * 64;
  const int h = (blockIdx.x >> 4) & 15;
  const int b = blockIdx.x >> 8;
  const int jr = t >> 2, ds = (t & 3) * 16;   // read row j0+jr, d-seg ds..ds+15 (coalesced)
  const float* src = kf + (size_t)(b * L_ + j0 + jr) * D_ + h * DH_ + ds;
  float4 v0 = ((const float4*)src)[0];
  float4 v1 = ((const float4*)src)[1];
  float4 v2 = ((const float4*)src)[2];
  float4 v3 = ((const float4*)src)[3];
  tile[ds + 0][jr] = v0.x;  tile[ds + 1][jr] = v0.y;  tile[ds + 2][jr] = v0.z;  tile[ds + 3][jr] = v0.w;
  tile[ds + 4][jr] = v1.x;  tile[ds + 5][jr] = v1.y;  tile[ds + 6][jr] = v1.z;  tile[ds + 7][jr] = v1.w;
  tile[ds + 8][jr] = v2.x;  tile[ds + 9][jr] = v2.y;  tile[ds + 10][jr] = v2.z; tile[ds + 11][jr] = v2.w;
  tile[ds + 12][jr] = v3.x; tile[ds + 13][jr] = v3.y; tile[ds + 14][jr] = v3.z; tile[ds + 15][jr] = v3.w;
  __syncthreads();
  const int dr = t >> 2, js = (t & 3) * 16;   // write d-row dr, j-seg js..js+15 (coalesced)
  float* dst = kT + ((size_t)(b * 16 + h) * 64 + dr) * 1024 + j0 + js;
  ((float4*)dst)[0] = *(const float4*)&tile[dr][js];
  ((float4*)dst)[1] = *(const float4*)&tile[dr][js + 4];
  ((float4*)dst)[2] = *(const float4*)&tile[dr][js + 8];
  ((float4*)dst)[3] = *(const float4*)&tile[dr][js + 12];
}

// ---------------- attention: d-split cooperative, coalesced kT loads ----------------
// grid: 16384 = 256 i-chunks x 16 h x 4 b; block 256 = 4 waves, 4 q-rows.
// Wave w owns d-slice [16w,16w+16); lane j loads kT[d][c*64+j] (coalesced),
// computes 4 rows' partials, exchanged via 8 KB LDS; wave w selects for row ib+w.
__global__ __launch_bounds__(256, 4) void attn_topk_f32(const float* __restrict__ qf,
                                                        const float* __restrict__ kT,
                                                        const float* __restrict__ vf,
                                                        float* __restrict__ aw) {
  __shared__ float part[2][4][4][64];   // [buf][src wave u][row r][j]
  __shared__ float qsh[4][64];
  const int t = threadIdx.x;
  const int lane = t & 63;
  const int w = t >> 6;
  const int blk = blockIdx.x;
  const int ib = (blk & 255) * 4;
  const int h = (blk >> 8) & 15;
  const int b = blk >> 12;
  const size_t rowbase = (size_t)b * L_;

  { int r = t >> 6, d = t & 63; qsh[r][d] = qf[(rowbase + ib + r) * D_ + h * DH_ + d]; }
  __syncthreads();

  // q fragments: 4 rows x 16 d (this wave's d-slice) — kept resident (<=128 VGPR)
  float qr[4][16];
#pragma unroll
  for (int r = 0; r < 4; r++)
#pragma unroll
    for (int p = 0; p < 4; p++) {
      float4 v = *(const float4*)&qsh[r][16 * w + 4 * p];
      qr[r][4 * p + 0] = v.x; qr[r][4 * p + 1] = v.y;
      qr[r][4 * p + 2] = v.z; qr[r][4 * p + 3] = v.w;
    }

  // kT base for this wave's d-slice: [16 d rows][1024 j]
  const float* ktb = kT + ((size_t)(b * 16 + h) * 64 + 16 * w) * 1024;

  float sc[16];
  for (int c = 0; c < 16; ++c) {
    const float* kp = ktb + c * 64 + lane;
    float kv[16];
#pragma unroll
    for (int dd = 0; dd < 16; dd++) kv[dd] = kp[(size_t)dd * 1024];
    float ps[4];
#pragma unroll
    for (int r = 0; r < 4; r++) {
      float s = 0.f;
#pragma unroll
      for (int dd = 0; dd < 16; dd++) s = fmaf(kv[dd], qr[r][dd], s);
      ps[r] = s;
    }
    const int pb = c & 1;
    part[pb][w][0][lane] = ps[0];
    part[pb][w][1][lane] = ps[1];
    part[pb][w][2][lane] = ps[2];
    part[pb][w][3][lane] = ps[3];
    __syncthreads();
    sc[c] = ((part[pb][0][w][lane] + part[pb][1][w][lane]) +
             (part[pb][2][w][lane] + part[pb][3][w][lane])) * 0.125f;
  }

  // ---- selection (identical numerics to R5/R7) ----
  float mx = sc[0];
#pragma unroll
  for (int u = 1; u < 16; u++) mx = fmaxf(mx, sc[u]);
#pragma unroll
  for (int off = 32; off >= 1; off >>= 1) mx = fmaxf(mx, __shfl_xor(mx, off, 64));

  float lo = mx - 64.f, hi = mx;
  for (int it = 0; it < 16; ++it) {
    float mid = 0.5f * (lo + hi);
    int cnt = 0;
#pragma unroll
    for (int u = 0; u < 16; u++) cnt += __popcll(__ballot(sc[u] >= mid));
    if (cnt >= 32) lo = mid; else hi = mid;
  }
  int cabove = 0;
#pragma unroll
  for (int u = 0; u < 16; u++) cabove += __popcll(__ballot(sc[u] >= hi));
  float v31 = hi;
  while (cabove < 32) {
    float nx = -INFINITY;
#pragma unroll
    for (int u = 0; u < 16; u++) nx = fmaxf(nx, (sc[u] < v31) ? sc[u] : -INFINITY);
#pragma unroll
    for (int off = 32; off >= 1; off >>= 1) nx = fmaxf(nx, __shfl_xor(nx, off, 64));
    int ceq = 0;
#pragma unroll
    for (int u = 0; u < 16; u++) ceq += __popcll(__ballot(sc[u] == nx));
    cabove += ceq;
    v31 = nx;
  }
  int c_eq = 0;
#pragma unroll
  for (int u = 0; u < 16; u++) c_eq += __popcll(__ballot(sc[u] == v31));
  const int c_gt = cabove - c_eq;
  const bool span = (cabove > 32);
  const int keep_eq = 32 - c_gt;
  float v32;
  if (span) {
    v32 = v31;
  } else {
    float nx = -INFINITY;
#pragma unroll
    for (int u = 0; u < 16; u++) nx = fmaxf(nx, (sc[u] < v31) ? sc[u] : -INFINITY);
#pragma unroll
    for (int off = 32; off >= 1; off >>= 1) nx = fmaxf(nx, __shfl_xor(nx, off, 64));
    v32 = nx;
  }
  const float tau = 0.5f * (v31 + v32);
  const float invbeta = 166666.67f;   // 1 / 6e-6

  float z = 0.f;
#pragma unroll
  for (int u = 0; u < 16; u++) z += __expf(sc[u] - mx);
#pragma unroll
  for (int off = 32; off >= 1; off >>= 1) z += __shfl_xor(z, off, 64);

  const float cutoff = fminf(tau - 1.8e-4f, v31);
  const float* vcol = vf + rowbase * D_ + h * DH_ + lane;
  float S = 0.f, acc = 0.f;
  int eq_seen = 0;
  for (int u = 0; u < 16; ++u) {
    unsigned long long mask = __ballot(sc[u] >= cutoff);
    while (mask) {
      int l2 = (int)__builtin_ctzll(mask);
      mask &= mask - 1;
      float s = __shfl(sc[u], l2, 64);
      float e = __expf(s - mx);
      float f;
      if (span) {
        if (s > v31) f = 1.f;
        else if (s == v31) { f = (eq_seen < keep_eq) ? 1.f : 0.f; ++eq_seen; }
        else f = 0.f;
      } else {
        float arg = (s - tau) * invbeta;
        f = (arg > 30.f) ? 1.f : ((arg < -30.f) ? 0.f : 1.f / (1.f + __expf(-arg)));
      }
      float fe = f * e;
      S += fe;
      acc = fmaf(fe, vcol[(size_t)(u * 64 + l2) * D_], acc);
    }
  }
  aw[(rowbase + ib + w) * D_ + h * DH_ + lane] = acc / (S + 1e-8f * z);
}

extern "C" void kernel_launch(void* const* d_in, const int* in_sizes, int n_in,
                              void* d_out, int out_size, void* d_ws, size_t ws_size,
                              hipStream_t stream) {
  const float* x  = (const float*)d_in[0];
  const float* Wq = (const float*)d_in[1];
  const float* bq = (const float*)d_in[2];
  const float* Wk = (const float*)d_in[3];
  const float* bk = (const float*)d_in[4];
  const float* Wv = (const float*)d_in[5];
  const float* bv = (const float*)d_in[6];
  const float* Wo = (const float*)d_in[7];
  const float* bo = (const float*)d_in[8];
  float* out = (float*)d_out;

  const size_t MD = (size_t)M_ * D_;
  float* qf = (float*)d_ws;            // 16 MB each; ws >= 96 MiB established
  float* kf = qf + MD;
  float* vf = kf + MD;
  float* aw = vf + MD;
  float* kT = aw + MD;                 // 16 MB, head-major transposed K

  dim3 b256(256);
  dim3 gqkv(8, 32, 3);
  dim3 g128(8, 32);
  dim3 gattn(16384);
  dim3 gtr(1024);

  hipLaunchKernelGGL(gemm_qkv, gqkv, b256, 0, stream,
                     x, Wq, bq, qf, Wk, bk, kf, Wv, bv, vf);
  hipLaunchKernelGGL(transpose_k, gtr, b256, 0, stream, kf, kT);
  hipLaunchKernelGGL(attn_topk_f32, gattn, b256, 0, stream, qf, kT, vf, aw);
  hipLaunchKernelGGL(gemm_out, g128, b256, 0, stream, aw, Wo, bo, out);
}

// Round 9
// 881.163 us; speedup vs baseline: 2.7767x; 1.0799x over previous
//
#include <hip/hip_runtime.h>
#include <math.h>

#define B_ 4
#define L_ 1024
#define D_ 1024
#define H_ 16
#define DH_ 64
#define M_ (B_*L_)   // 4096 rows

// ---------------- fp32 128x128-tile GEMM, BK=16, reg-prefetch ----------------
__device__ __forceinline__ void gemm128_body(const float* __restrict__ A,
                                             const float* __restrict__ W,
                                             const float* __restrict__ bias,
                                             float* __restrict__ C) {
  __shared__ float As[16][128];
  __shared__ float Bs[16][128];
  const int t = threadIdx.x;
  const int bm = blockIdx.y * 128, bn = blockIdx.x * 128;
  const int tx = t & 15, ty = t >> 4;
  float acc[8][8];
#pragma unroll
  for (int i = 0; i < 8; i++)
#pragma unroll
    for (int j = 0; j < 8; j++) acc[i][j] = 0.f;
  const int ar = t >> 1, ac = (t & 1) * 8;
  const int wr = t >> 4, wc = (t & 15) * 8;
  const float* Ap = A + (size_t)(bm + ar) * 1024 + ac;
  const float* Wp = W + (size_t)wr * 1024 + bn + wc;
  float4 a0 = *(const float4*)(Ap);
  float4 a1 = *(const float4*)(Ap + 4);
  float4 w0 = *(const float4*)(Wp);
  float4 w1 = *(const float4*)(Wp + 4);
  for (int k0 = 0; k0 < 1024; k0 += 16) {
    __syncthreads();
    As[ac + 0][ar] = a0.x; As[ac + 1][ar] = a0.y;
    As[ac + 2][ar] = a0.z; As[ac + 3][ar] = a0.w;
    As[ac + 4][ar] = a1.x; As[ac + 5][ar] = a1.y;
    As[ac + 6][ar] = a1.z; As[ac + 7][ar] = a1.w;
    *(float4*)&Bs[wr][wc] = w0;
    *(float4*)&Bs[wr][wc + 4] = w1;
    __syncthreads();
    if (k0 + 16 < 1024) {
      a0 = *(const float4*)(Ap + k0 + 16);
      a1 = *(const float4*)(Ap + k0 + 20);
      w0 = *(const float4*)(Wp + (size_t)(k0 + 16) * 1024);
      w1 = *(const float4*)(Wp + (size_t)(k0 + 16) * 1024 + 4);
    }
#pragma unroll
    for (int k = 0; k < 16; k++) {
      float4 x0 = *(const float4*)&As[k][ty * 8];
      float4 x1 = *(const float4*)&As[k][ty * 8 + 4];
      float4 y0 = *(const float4*)&Bs[k][tx * 8];
      float4 y1 = *(const float4*)&Bs[k][tx * 8 + 4];
      float a_[8] = {x0.x, x0.y, x0.z, x0.w, x1.x, x1.y, x1.z, x1.w};
      float b_[8] = {y0.x, y0.y, y0.z, y0.w, y1.x, y1.y, y1.z, y1.w};
#pragma unroll
      for (int i = 0; i < 8; i++)
#pragma unroll
        for (int j = 0; j < 8; j++)
          acc[i][j] = fmaf(a_[i], b_[j], acc[i][j]);
    }
  }
#pragma unroll
  for (int i = 0; i < 8; i++) {
    int m = bm + ty * 8 + i;
    float* Cp = C + (size_t)m * 1024 + bn + tx * 8;
    const float* bp = bias + bn + tx * 8;
#pragma unroll
    for (int j = 0; j < 8; j++) Cp[j] = acc[i][j] + bp[j];
  }
}

__global__ __launch_bounds__(256) void gemm_qkv(const float* __restrict__ x,
                                                const float* __restrict__ Wq, const float* __restrict__ bq, float* __restrict__ qf,
                                                const float* __restrict__ Wk, const float* __restrict__ bk, float* __restrict__ kf,
                                                const float* __restrict__ Wv, const float* __restrict__ bv, float* __restrict__ vf) {
  const int z = blockIdx.z;
  const float* W = (z == 0) ? Wq : (z == 1) ? Wk : Wv;
  const float* bb = (z == 0) ? bq : (z == 1) ? bk : bv;
  float* C = (z == 0) ? qf : (z == 1) ? kf : vf;
  gemm128_body(x, W, bb, C);
}

__global__ __launch_bounds__(256) void gemm_out(const float* __restrict__ A,
                                                const float* __restrict__ W,
                                                const float* __restrict__ bias,
                                                float* __restrict__ C) {
  gemm128_body(A, W, bias, C);
}

// ---------------- K transpose, chunk-tiled: kf[b*L+j][h*64+d] ->
// kT[((b*16+h)*16 + c)*4096 + d*64 + j']   (j = c*64+j') ----------------
__global__ __launch_bounds__(256) void transpose_k(const float* __restrict__ kf,
                                                   float* __restrict__ kT) {
  __shared__ float tile[64][65];
  const int t = threadIdx.x;
  const int c = blockIdx.x & 15;
  const int h = (blockIdx.x >> 4) & 15;
  const int b = blockIdx.x >> 8;
  const int j0 = c * 64;
  const int jr = t >> 2, ds = (t & 3) * 16;
  const float* src = kf + (size_t)(b * L_ + j0 + jr) * D_ + h * DH_ + ds;
  float4 v0 = ((const float4*)src)[0];
  float4 v1 = ((const float4*)src)[1];
  float4 v2 = ((const float4*)src)[2];
  float4 v3 = ((const float4*)src)[3];
  tile[ds + 0][jr] = v0.x;  tile[ds + 1][jr] = v0.y;  tile[ds + 2][jr] = v0.z;  tile[ds + 3][jr] = v0.w;
  tile[ds + 4][jr] = v1.x;  tile[ds + 5][jr] = v1.y;  tile[ds + 6][jr] = v1.z;  tile[ds + 7][jr] = v1.w;
  tile[ds + 8][jr] = v2.x;  tile[ds + 9][jr] = v2.y;  tile[ds + 10][jr] = v2.z; tile[ds + 11][jr] = v2.w;
  tile[ds + 12][jr] = v3.x; tile[ds + 13][jr] = v3.y; tile[ds + 14][jr] = v3.z; tile[ds + 15][jr] = v3.w;
  __syncthreads();
  const int dr = t >> 2, js = (t & 3) * 16;
  float* dst = kT + ((size_t)((b * 16 + h) * 16 + c)) * 4096 + dr * 64 + js;
  ((float4*)dst)[0] = *(const float4*)&tile[dr][js];
  ((float4*)dst)[1] = *(const float4*)&tile[dr][js + 4];
  ((float4*)dst)[2] = *(const float4*)&tile[dr][js + 8];
  ((float4*)dst)[3] = *(const float4*)&tile[dr][js + 12];
}

// ---------------- attention: d-split cooperative, chunk-tiled kT, batched barriers ----------------
// grid: 16384 = 256 i-chunks x 16 h x 4 b; block 256 = 4 waves, 4 q-rows.
// Wave w owns d-slice [16w,16w+16); 4 chunks per barrier pair; partials via
// part2[c4][r][j][u] (combine = 1 ds_read_b128). Selection vectorized e/f.
__global__ __launch_bounds__(256, 4) void attn_topk_f32(const float* __restrict__ qf,
                                                        const float* __restrict__ kT,
                                                        const float* __restrict__ vf,
                                                        float* __restrict__ aw) {
  __shared__ float part2[4][4][64][4];   // [c4][row r][j][src wave u]  16 KB
  __shared__ float qsh[4][64];
  const int t = threadIdx.x;
  const int lane = t & 63;
  const int w = t >> 6;
  const int blk = blockIdx.x;
  const int ib = (blk & 255) * 4;
  const int h = (blk >> 8) & 15;
  const int b = blk >> 12;
  const size_t rowbase = (size_t)b * L_;

  { int r = t >> 6, d = t & 63; qsh[r][d] = qf[(rowbase + ib + r) * D_ + h * DH_ + d]; }
  __syncthreads();

  float qr[4][16];
#pragma unroll
  for (int r = 0; r < 4; r++)
#pragma unroll
    for (int p = 0; p < 4; p++) {
      float4 v = *(const float4*)&qsh[r][16 * w + 4 * p];
      qr[r][4 * p + 0] = v.x; qr[r][4 * p + 1] = v.y;
      qr[r][4 * p + 2] = v.z; qr[r][4 * p + 3] = v.w;
    }

  // chunk-tiled kT base for this wave's d-slice
  const float* ktb = kT + ((size_t)(b * 16 + h) * 16) * 4096 + (16 * w) * 64;

  float sc[16];
#pragma unroll
  for (int s = 0; s < 4; ++s) {
    // compute phase: 4 chunks, 64 loads in flight
#pragma unroll
    for (int c4 = 0; c4 < 4; ++c4) {
      const int c = s * 4 + c4;
      const float* kp = ktb + (size_t)c * 4096 + lane;
      float kv[16];
#pragma unroll
      for (int dd = 0; dd < 16; dd++) kv[dd] = kp[dd * 64];   // imm offsets
      float ps[4];
#pragma unroll
      for (int r = 0; r < 4; r++) {
        float sacc = 0.f;
#pragma unroll
        for (int dd = 0; dd < 16; dd++) sacc = fmaf(kv[dd], qr[r][dd], sacc);
        ps[r] = sacc;
      }
      part2[c4][0][lane][w] = ps[0];
      part2[c4][1][lane][w] = ps[1];
      part2[c4][2][lane][w] = ps[2];
      part2[c4][3][lane][w] = ps[3];
    }
    __syncthreads();
#pragma unroll
    for (int c4 = 0; c4 < 4; ++c4) {
      float4 p = *(const float4*)&part2[c4][w][lane][0];
      sc[s * 4 + c4] = ((p.x + p.y) + (p.z + p.w)) * 0.125f;
    }
    __syncthreads();   // combine reads done before next phase overwrites
  }

  // ---- max
  float mx = sc[0];
#pragma unroll
  for (int u = 1; u < 16; u++) mx = fmaxf(mx, sc[u]);
#pragma unroll
  for (int off = 32; off >= 1; off >>= 1) mx = fmaxf(mx, __shfl_xor(mx, off, 64));

  // ---- bisection (window mx-16, 14 iters; descent below is exact anyway)
  float lo = mx - 16.f, hi = mx;
  for (int it = 0; it < 14; ++it) {
    float mid = 0.5f * (lo + hi);
    int cnt = 0;
#pragma unroll
    for (int u = 0; u < 16; u++) cnt += __popcll(__ballot(sc[u] >= mid));
    if (cnt >= 32) lo = mid; else hi = mid;
  }
  // ---- descend to exact rank-31 value, duplicate-aware
  int cabove = 0;
#pragma unroll
  for (int u = 0; u < 16; u++) cabove += __popcll(__ballot(sc[u] >= hi));
  float v31 = hi;
  while (cabove < 32) {
    float nx = -INFINITY;
#pragma unroll
    for (int u = 0; u < 16; u++) nx = fmaxf(nx, (sc[u] < v31) ? sc[u] : -INFINITY);
#pragma unroll
    for (int off = 32; off >= 1; off >>= 1) nx = fmaxf(nx, __shfl_xor(nx, off, 64));
    int ceq = 0;
#pragma unroll
    for (int u = 0; u < 16; u++) ceq += __popcll(__ballot(sc[u] == nx));
    cabove += ceq;
    v31 = nx;
  }
  int c_eq = 0;
#pragma unroll
  for (int u = 0; u < 16; u++) c_eq += __popcll(__ballot(sc[u] == v31));
  const int c_gt = cabove - c_eq;
  const bool span = (cabove > 32);
  const int keep_eq = 32 - c_gt;
  float v32;
  if (span) {
    v32 = v31;
  } else {
    float nx = -INFINITY;
#pragma unroll
    for (int u = 0; u < 16; u++) nx = fmaxf(nx, (sc[u] < v31) ? sc[u] : -INFINITY);
#pragma unroll
    for (int off = 32; off >= 1; off >>= 1) nx = fmaxf(nx, __shfl_xor(nx, off, 64));
    v32 = nx;
  }
  const float tau = 0.5f * (v31 + v32);
  const float invbeta = 166666.67f;   // 1 / 6e-6

  // ---- e[u] (vectorized; reused by Z and enumeration)
  float e[16];
#pragma unroll
  for (int u = 0; u < 16; u++) e[u] = __expf(sc[u] - mx);
  float z = 0.f;
#pragma unroll
  for (int u = 0; u < 16; u++) z += e[u];
#pragma unroll
  for (int off = 32; off >= 1; off >>= 1) z += __shfl_xor(z, off, 64);

  // ---- f weights vectorized (non-span fast path)
  float fw[16];
  if (!span) {
#pragma unroll
    for (int u = 0; u < 16; u++) {
      float arg = (sc[u] - tau) * invbeta;
      fw[u] = (arg > 30.f) ? 1.f : ((arg < -30.f) ? 0.f : 1.f / (1.f + __expf(-arg)));
    }
  }

  // ---- enumerate candidates, accumulate V (order identical to R8)
  const float cutoff = fminf(tau - 1.8e-4f, v31);
  const float* vcol = vf + rowbase * D_ + h * DH_ + lane;
  float S = 0.f, acc = 0.f;
  int eq_seen = 0;
  for (int u = 0; u < 16; ++u) {
    unsigned long long mask = __ballot(sc[u] >= cutoff);
    while (mask) {
      int l2 = (int)__builtin_ctzll(mask);
      mask &= mask - 1;
      float e_ = __shfl(e[u], l2, 64);
      float f_;
      if (span) {
        float s_ = __shfl(sc[u], l2, 64);
        if (s_ > v31) f_ = 1.f;
        else if (s_ == v31) { f_ = (eq_seen < keep_eq) ? 1.f : 0.f; ++eq_seen; }
        else f_ = 0.f;
      } else {
        f_ = __shfl(fw[u], l2, 64);
      }
      float fe = f_ * e_;
      S += fe;
      acc = fmaf(fe, vcol[(size_t)(u * 64 + l2) * D_], acc);
    }
  }
  aw[(rowbase + ib + w) * D_ + h * DH_ + lane] = acc / (S + 1e-8f * z);
}

extern "C" void kernel_launch(void* const* d_in, const int* in_sizes, int n_in,
                              void* d_out, int out_size, void* d_ws, size_t ws_size,
                              hipStream_t stream) {
  const float* x  = (const float*)d_in[0];
  const float* Wq = (const float*)d_in[1];
  const float* bq = (const float*)d_in[2];
  const float* Wk = (const float*)d_in[3];
  const float* bk = (const float*)d_in[4];
  const float* Wv = (const float*)d_in[5];
  const float* bv = (const float*)d_in[6];
  const float* Wo = (const float*)d_in[7];
  const float* bo = (const float*)d_in[8];
  float* out = (float*)d_out;

  const size_t MD = (size_t)M_ * D_;
  float* qf = (float*)d_ws;            // 5 x 16 MB; ws >= 80 MB established (R4..R8)
  float* kf = qf + MD;
  float* vf = kf + MD;
  float* aw = vf + MD;
  float* kT = aw + MD;

  dim3 b256(256);
  dim3 gqkv(8, 32, 3);
  dim3 g128(8, 32);
  dim3 gattn(16384);
  dim3 gtr(1024);

  hipLaunchKernelGGL(gemm_qkv, gqkv, b256, 0, stream,
                     x, Wq, bq, qf, Wk, bk, kf, Wv, bv, vf);
  hipLaunchKernelGGL(transpose_k, gtr, b256, 0, stream, kf, kT);
  hipLaunchKernelGGL(attn_topk_f32, gattn, b256, 0, stream, qf, kT, vf, aw);
  hipLaunchKernelGGL(gemm_out, g128, b256, 0, stream, aw, Wo, bo, out);
}

// Round 10
// 787.672 us; speedup vs baseline: 3.1062x; 1.1187x over previous
//
#include <hip/hip_runtime.h>
#include <math.h>

#define B_ 4
#define L_ 1024
#define D_ 1024
#define H_ 16
#define DH_ 64
#define M_ (B_*L_)   // 4096 rows

// ---------------- fp32 128x128-tile GEMM, BK=16, double-buffered LDS ----------------
// One barrier per K-step: write next tile to buf p^1 (prev reads of p^1 ended
// before last barrier), compute from p.
__device__ __forceinline__ void gemm128_body(const float* __restrict__ A,
                                             const float* __restrict__ W,
                                             const float* __restrict__ bias,
                                             float* __restrict__ C) {
  __shared__ float As[2][16][128];
  __shared__ float Bs[2][16][128];
  const int t = threadIdx.x;
  const int bm = blockIdx.y * 128, bn = blockIdx.x * 128;
  const int tx = t & 15, ty = t >> 4;
  float acc[8][8];
#pragma unroll
  for (int i = 0; i < 8; i++)
#pragma unroll
    for (int j = 0; j < 8; j++) acc[i][j] = 0.f;
  const int ar = t >> 1, ac = (t & 1) * 8;
  const int wr = t >> 4, wc = (t & 15) * 8;
  const float* Ap = A + (size_t)(bm + ar) * 1024 + ac;
  const float* Wp = W + (size_t)wr * 1024 + bn + wc;
  float4 a0 = *(const float4*)(Ap);
  float4 a1 = *(const float4*)(Ap + 4);
  float4 w0 = *(const float4*)(Wp);
  float4 w1 = *(const float4*)(Wp + 4);
  // prologue: stage tile 0 into buf 0
  As[0][ac + 0][ar] = a0.x; As[0][ac + 1][ar] = a0.y;
  As[0][ac + 2][ar] = a0.z; As[0][ac + 3][ar] = a0.w;
  As[0][ac + 4][ar] = a1.x; As[0][ac + 5][ar] = a1.y;
  As[0][ac + 6][ar] = a1.z; As[0][ac + 7][ar] = a1.w;
  *(float4*)&Bs[0][wr][wc] = w0;
  *(float4*)&Bs[0][wr][wc + 4] = w1;
  __syncthreads();
  int p = 0;
  for (int k0 = 0; k0 < 1024; k0 += 16) {
    const bool more = (k0 + 16 < 1024);
    if (more) {
      a0 = *(const float4*)(Ap + k0 + 16);
      a1 = *(const float4*)(Ap + k0 + 20);
      w0 = *(const float4*)(Wp + (size_t)(k0 + 16) * 1024);
      w1 = *(const float4*)(Wp + (size_t)(k0 + 16) * 1024 + 4);
    }
#pragma unroll
    for (int k = 0; k < 16; k++) {
      float4 x0 = *(const float4*)&As[p][k][ty * 8];
      float4 x1 = *(const float4*)&As[p][k][ty * 8 + 4];
      float4 y0 = *(const float4*)&Bs[p][k][tx * 8];
      float4 y1 = *(const float4*)&Bs[p][k][tx * 8 + 4];
      float a_[8] = {x0.x, x0.y, x0.z, x0.w, x1.x, x1.y, x1.z, x1.w};
      float b_[8] = {y0.x, y0.y, y0.z, y0.w, y1.x, y1.y, y1.z, y1.w};
#pragma unroll
      for (int i = 0; i < 8; i++)
#pragma unroll
        for (int j = 0; j < 8; j++)
          acc[i][j] = fmaf(a_[i], b_[j], acc[i][j]);
    }
    if (more) {
      const int q = p ^ 1;
      As[q][ac + 0][ar] = a0.x; As[q][ac + 1][ar] = a0.y;
      As[q][ac + 2][ar] = a0.z; As[q][ac + 3][ar] = a0.w;
      As[q][ac + 4][ar] = a1.x; As[q][ac + 5][ar] = a1.y;
      As[q][ac + 6][ar] = a1.z; As[q][ac + 7][ar] = a1.w;
      *(float4*)&Bs[q][wr][wc] = w0;
      *(float4*)&Bs[q][wr][wc + 4] = w1;
      __syncthreads();
      p = q;
    }
  }
#pragma unroll
  for (int i = 0; i < 8; i++) {
    int m = bm + ty * 8 + i;
    float* Cp = C + (size_t)m * 1024 + bn + tx * 8;
    const float* bp = bias + bn + tx * 8;
#pragma unroll
    for (int j = 0; j < 8; j++) Cp[j] = acc[i][j] + bp[j];
  }
}

__global__ __launch_bounds__(256) void gemm_qkv(const float* __restrict__ x,
                                                const float* __restrict__ Wq, const float* __restrict__ bq, float* __restrict__ qf,
                                                const float* __restrict__ Wk, const float* __restrict__ bk, float* __restrict__ kf,
                                                const float* __restrict__ Wv, const float* __restrict__ bv, float* __restrict__ vf) {
  const int z = blockIdx.z;
  const float* W = (z == 0) ? Wq : (z == 1) ? Wk : Wv;
  const float* bb = (z == 0) ? bq : (z == 1) ? bk : bv;
  float* C = (z == 0) ? qf : (z == 1) ? kf : vf;
  gemm128_body(x, W, bb, C);
}

__global__ __launch_bounds__(256) void gemm_out(const float* __restrict__ A,
                                                const float* __restrict__ W,
                                                const float* __restrict__ bias,
                                                float* __restrict__ C) {
  gemm128_body(A, W, bias, C);
}

// ---------------- K transpose, chunk-tiled: kf[b*L+j][h*64+d] ->
// kT[((b*16+h)*16 + c)*4096 + d*64 + j']   (j = c*64+j') ----------------
__global__ __launch_bounds__(256) void transpose_k(const float* __restrict__ kf,
                                                   float* __restrict__ kT) {
  __shared__ float tile[64][65];
  const int t = threadIdx.x;
  const int c = blockIdx.x & 15;
  const int h = (blockIdx.x >> 4) & 15;
  const int b = blockIdx.x >> 8;
  const int j0 = c * 64;
  const int jr = t >> 2, ds = (t & 3) * 16;
  const float* src = kf + (size_t)(b * L_ + j0 + jr) * D_ + h * DH_ + ds;
  float4 v0 = ((const float4*)src)[0];
  float4 v1 = ((const float4*)src)[1];
  float4 v2 = ((const float4*)src)[2];
  float4 v3 = ((const float4*)src)[3];
  tile[ds + 0][jr] = v0.x;  tile[ds + 1][jr] = v0.y;  tile[ds + 2][jr] = v0.z;  tile[ds + 3][jr] = v0.w;
  tile[ds + 4][jr] = v1.x;  tile[ds + 5][jr] = v1.y;  tile[ds + 6][jr] = v1.z;  tile[ds + 7][jr] = v1.w;
  tile[ds + 8][jr] = v2.x;  tile[ds + 9][jr] = v2.y;  tile[ds + 10][jr] = v2.z; tile[ds + 11][jr] = v2.w;
  tile[ds + 12][jr] = v3.x; tile[ds + 13][jr] = v3.y; tile[ds + 14][jr] = v3.z; tile[ds + 15][jr] = v3.w;
  __syncthreads();
  const int dr = t >> 2, js = (t & 3) * 16;
  float* dst = kT + ((size_t)((b * 16 + h) * 16 + c)) * 4096 + dr * 64 + js;
  ((float4*)dst)[0] = *(const float4*)&tile[dr][js];
  ((float4*)dst)[1] = *(const float4*)&tile[dr][js + 4];
  ((float4*)dst)[2] = *(const float4*)&tile[dr][js + 8];
  ((float4*)dst)[3] = *(const float4*)&tile[dr][js + 12];
}

// ---------------- attention: d-split cooperative, q in SGPRs ----------------
// grid: 16384 = 256 i-chunks x 16 h x 4 b; block 256 = 4 waves, 4 q-rows.
// Wave w owns d-slice [16w,16w+16). q fragments are wave-uniform -> moved to
// SGPRs via readfirstlane into 64 DISCRETE named scalars (R6's array form got
// scratch-allocated; discrete scalars force SGPR). FMA order identical to R9.
#define RFL(x) __int_as_float(__builtin_amdgcn_readfirstlane(__float_as_int(x)))
#define LQROW(r) \
  const float q##r##_0  = RFL(qsh[r][qo +  0]), q##r##_1  = RFL(qsh[r][qo +  1]), \
              q##r##_2  = RFL(qsh[r][qo +  2]), q##r##_3  = RFL(qsh[r][qo +  3]), \
              q##r##_4  = RFL(qsh[r][qo +  4]), q##r##_5  = RFL(qsh[r][qo +  5]), \
              q##r##_6  = RFL(qsh[r][qo +  6]), q##r##_7  = RFL(qsh[r][qo +  7]), \
              q##r##_8  = RFL(qsh[r][qo +  8]), q##r##_9  = RFL(qsh[r][qo +  9]), \
              q##r##_10 = RFL(qsh[r][qo + 10]), q##r##_11 = RFL(qsh[r][qo + 11]), \
              q##r##_12 = RFL(qsh[r][qo + 12]), q##r##_13 = RFL(qsh[r][qo + 13]), \
              q##r##_14 = RFL(qsh[r][qo + 14]), q##r##_15 = RFL(qsh[r][qo + 15]);
#define DOT16(r, sacc) \
  sacc = fmaf(kv0,  q##r##_0,  sacc); sacc = fmaf(kv1,  q##r##_1,  sacc); \
  sacc = fmaf(kv2,  q##r##_2,  sacc); sacc = fmaf(kv3,  q##r##_3,  sacc); \
  sacc = fmaf(kv4,  q##r##_4,  sacc); sacc = fmaf(kv5,  q##r##_5,  sacc); \
  sacc = fmaf(kv6,  q##r##_6,  sacc); sacc = fmaf(kv7,  q##r##_7,  sacc); \
  sacc = fmaf(kv8,  q##r##_8,  sacc); sacc = fmaf(kv9,  q##r##_9,  sacc); \
  sacc = fmaf(kv10, q##r##_10, sacc); sacc = fmaf(kv11, q##r##_11, sacc); \
  sacc = fmaf(kv12, q##r##_12, sacc); sacc = fmaf(kv13, q##r##_13, sacc); \
  sacc = fmaf(kv14, q##r##_14, sacc); sacc = fmaf(kv15, q##r##_15, sacc);

__global__ __launch_bounds__(256, 4) void attn_topk_f32(const float* __restrict__ qf,
                                                        const float* __restrict__ kT,
                                                        const float* __restrict__ vf,
                                                        float* __restrict__ aw) {
  __shared__ float part2[4][4][64][4];   // [c4][row r][j][src wave u]  16 KB
  __shared__ float qsh[4][64];
  const int t = threadIdx.x;
  const int lane = t & 63;
  const int w = t >> 6;
  const int blk = blockIdx.x;
  const int ib = (blk & 255) * 4;
  const int h = (blk >> 8) & 15;
  const int b = blk >> 12;
  const size_t rowbase = (size_t)b * L_;

  { int r = t >> 6, d = t & 63; qsh[r][d] = qf[(rowbase + ib + r) * D_ + h * DH_ + d]; }
  __syncthreads();

  const int qo = 16 * w;
  LQROW(0) LQROW(1) LQROW(2) LQROW(3)

  // chunk-tiled kT base for this wave's d-slice
  const float* ktb = kT + ((size_t)(b * 16 + h) * 16) * 4096 + qo * 64;

  float sc[16];
#pragma unroll
  for (int s = 0; s < 4; ++s) {
#pragma unroll
    for (int c4 = 0; c4 < 4; ++c4) {
      const int c = s * 4 + c4;
      const float* kp = ktb + (size_t)c * 4096 + lane;
      const float kv0 = kp[0 * 64],  kv1 = kp[1 * 64],  kv2 = kp[2 * 64],  kv3 = kp[3 * 64],
                  kv4 = kp[4 * 64],  kv5 = kp[5 * 64],  kv6 = kp[6 * 64],  kv7 = kp[7 * 64],
                  kv8 = kp[8 * 64],  kv9 = kp[9 * 64],  kv10 = kp[10 * 64], kv11 = kp[11 * 64],
                  kv12 = kp[12 * 64], kv13 = kp[13 * 64], kv14 = kp[14 * 64], kv15 = kp[15 * 64];
      float p0 = 0.f, p1 = 0.f, p2 = 0.f, p3 = 0.f;
      DOT16(0, p0) DOT16(1, p1) DOT16(2, p2) DOT16(3, p3)
      part2[c4][0][lane][w] = p0;
      part2[c4][1][lane][w] = p1;
      part2[c4][2][lane][w] = p2;
      part2[c4][3][lane][w] = p3;
    }
    __syncthreads();
#pragma unroll
    for (int c4 = 0; c4 < 4; ++c4) {
      float4 p = *(const float4*)&part2[c4][w][lane][0];
      sc[s * 4 + c4] = ((p.x + p.y) + (p.z + p.w)) * 0.125f;
    }
    __syncthreads();
  }

  // ---- max
  float mx = sc[0];
#pragma unroll
  for (int u = 1; u < 16; u++) mx = fmaxf(mx, sc[u]);
#pragma unroll
  for (int off = 32; off >= 1; off >>= 1) mx = fmaxf(mx, __shfl_xor(mx, off, 64));

  // ---- bisection (window mx-16, 14 iters; exact descent below)
  float lo = mx - 16.f, hi = mx;
  for (int it = 0; it < 14; ++it) {
    float mid = 0.5f * (lo + hi);
    int cnt = 0;
#pragma unroll
    for (int u = 0; u < 16; u++) cnt += __popcll(__ballot(sc[u] >= mid));
    if (cnt >= 32) lo = mid; else hi = mid;
  }
  int cabove = 0;
#pragma unroll
  for (int u = 0; u < 16; u++) cabove += __popcll(__ballot(sc[u] >= hi));
  float v31 = hi;
  while (cabove < 32) {
    float nx = -INFINITY;
#pragma unroll
    for (int u = 0; u < 16; u++) nx = fmaxf(nx, (sc[u] < v31) ? sc[u] : -INFINITY);
#pragma unroll
    for (int off = 32; off >= 1; off >>= 1) nx = fmaxf(nx, __shfl_xor(nx, off, 64));
    int ceq = 0;
#pragma unroll
    for (int u = 0; u < 16; u++) ceq += __popcll(__ballot(sc[u] == nx));
    cabove += ceq;
    v31 = nx;
  }
  int c_eq = 0;
#pragma unroll
  for (int u = 0; u < 16; u++) c_eq += __popcll(__ballot(sc[u] == v31));
  const int c_gt = cabove - c_eq;
  const bool span = (cabove > 32);
  const int keep_eq = 32 - c_gt;
  float v32;
  if (span) {
    v32 = v31;
  } else {
    float nx = -INFINITY;
#pragma unroll
    for (int u = 0; u < 16; u++) nx = fmaxf(nx, (sc[u] < v31) ? sc[u] : -INFINITY);
#pragma unroll
    for (int off = 32; off >= 1; off >>= 1) nx = fmaxf(nx, __shfl_xor(nx, off, 64));
    v32 = nx;
  }
  const float tau = 0.5f * (v31 + v32);
  const float invbeta = 166666.67f;   // 1 / 6e-6

  // ---- e[u] (vectorized; reused by Z and enumeration)
  float e[16];
#pragma unroll
  for (int u = 0; u < 16; u++) e[u] = __expf(sc[u] - mx);
  float z = 0.f;
#pragma unroll
  for (int u = 0; u < 16; u++) z += e[u];
#pragma unroll
  for (int off = 32; off >= 1; off >>= 1) z += __shfl_xor(z, off, 64);

  // ---- f weights vectorized (non-span fast path)
  float fw[16];
  if (!span) {
#pragma unroll
    for (int u = 0; u < 16; u++) {
      float arg = (sc[u] - tau) * invbeta;
      fw[u] = (arg > 30.f) ? 1.f : ((arg < -30.f) ? 0.f : 1.f / (1.f + __expf(-arg)));
    }
  }

  // ---- enumerate candidates, accumulate V
  const float cutoff = fminf(tau - 1.8e-4f, v31);
  const float* vcol = vf + rowbase * D_ + h * DH_ + lane;
  float S = 0.f, acc = 0.f;
  int eq_seen = 0;
  for (int u = 0; u < 16; ++u) {
    unsigned long long mask = __ballot(sc[u] >= cutoff);
    while (mask) {
      int l2 = (int)__builtin_ctzll(mask);
      mask &= mask - 1;
      float e_ = __shfl(e[u], l2, 64);
      float f_;
      if (span) {
        float s_ = __shfl(sc[u], l2, 64);
        if (s_ > v31) f_ = 1.f;
        else if (s_ == v31) { f_ = (eq_seen < keep_eq) ? 1.f : 0.f; ++eq_seen; }
        else f_ = 0.f;
      } else {
        f_ = __shfl(fw[u], l2, 64);
      }
      float fe = f_ * e_;
      S += fe;
      acc = fmaf(fe, vcol[(size_t)(u * 64 + l2) * D_], acc);
    }
  }
  aw[(rowbase + ib + w) * D_ + h * DH_ + lane] = acc / (S + 1e-8f * z);
}

extern "C" void kernel_launch(void* const* d_in, const int* in_sizes, int n_in,
                              void* d_out, int out_size, void* d_ws, size_t ws_size,
                              hipStream_t stream) {
  const float* x  = (const float*)d_in[0];
  const float* Wq = (const float*)d_in[1];
  const float* bq = (const float*)d_in[2];
  const float* Wk = (const float*)d_in[3];
  const float* bk = (const float*)d_in[4];
  const float* Wv = (const float*)d_in[5];
  const float* bv = (const float*)d_in[6];
  const float* Wo = (const float*)d_in[7];
  const float* bo = (const float*)d_in[8];
  float* out = (float*)d_out;

  const size_t MD = (size_t)M_ * D_;
  float* qf = (float*)d_ws;            // 5 x 16 MB; ws >= 80 MB established
  float* kf = qf + MD;
  float* vf = kf + MD;
  float* aw = vf + MD;
  float* kT = aw + MD;

  dim3 b256(256);
  dim3 gqkv(8, 32, 3);
  dim3 g128(8, 32);
  dim3 gattn(16384);
  dim3 gtr(1024);

  hipLaunchKernelGGL(gemm_qkv, gqkv, b256, 0, stream,
                     x, Wq, bq, qf, Wk, bk, kf, Wv, bv, vf);
  hipLaunchKernelGGL(transpose_k, gtr, b256, 0, stream, kf, kT);
  hipLaunchKernelGGL(attn_topk_f32, gattn, b256, 0, stream, qf, kT, vf, aw);
  hipLaunchKernelGGL(gemm_out, g128, b256, 0, stream, aw, Wo, bo, out);
}